// Round 1
// baseline (281.261 us; speedup 1.0000x reference)
//
#include <hip/hip_runtime.h>

// Problem constants (fixed by setup_inputs: B=64, C=16, T=32768, fp32)
#define B_BATCH 64
#define C_CH    16
#define T_LEN   32768
#define THREADS 256
#define VEC     4
#define CHUNK   (THREADS * VEC)     // 1024 elements per chunk
#define NCHUNK  (T_LEN / CHUNK)     // 32 chunks per row
#define NROWS   (B_BATCH * C_CH)    // 1024 rows -> 1024 blocks (4 per CU)

__global__ __launch_bounds__(THREADS) void wloss_scan_kernel(
    const float* __restrict__ pred,
    const float* __restrict__ tru,
    double* __restrict__ ws_accum)
{
    const int row  = blockIdx.x;             // one block per (b, c) row
    const int tid  = threadIdx.x;
    const int lane = tid & 63;
    const int wave = tid >> 6;               // 4 waves per block

    const float4* p4 = (const float4*)(pred + (size_t)row * T_LEN);
    const float4* t4 = (const float4*)(tru  + (size_t)row * T_LEN);

    // parity double-buffered wave-total exchange -> one barrier per chunk
    __shared__ float wtot[2][4];

    float  carry = 0.0f;   // running cumsum at chunk start (replicated per thread)
    double acc   = 0.0;    // per-thread weighted-|cumsum| accumulator

    for (int ch = 0; ch < NCHUNK; ++ch) {
        // coalesced float4 load: thread i covers elements [chunk + 4i, chunk + 4i + 4)
        const int v4idx = ch * (CHUNK / VEC) + tid;
        float4 p = p4[v4idx];
        float4 t = t4[v4idx];

        float d0 = p.x - t.x;
        float d1 = p.y - t.y;
        float d2 = p.z - t.z;
        float d3 = p.w - t.w;

        // local inclusive scan of the 4 diffs
        float s1 = d0;
        float s2 = s1 + d1;
        float s3 = s2 + d2;
        float s4 = s3 + d3;

        // wave-level inclusive scan of per-thread sums (64 lanes)
        float v = s4;
        #pragma unroll
        for (int off = 1; off < 64; off <<= 1) {
            float u = __shfl_up(v, off, 64);
            if (lane >= off) v += u;
        }

        const int par = ch & 1;
        if (lane == 63) wtot[par][wave] = v;
        __syncthreads();

        float wprefix = 0.0f;   // sum of totals of earlier waves
        float total   = 0.0f;   // whole-chunk total
        #pragma unroll
        for (int w = 0; w < 4; ++w) {
            float wt = wtot[par][w];
            if (w < wave) wprefix += wt;
            total += wt;
        }

        // exclusive prefix for this thread's first element (global over the row)
        const float excl = carry + wprefix + (v - s4);

        const int   e  = ch * CHUNK + tid * VEC;     // global element index of d0
        const float w0 = (float)(T_LEN - e);         // weight for element e

        float c1 = excl + s1;
        float c2 = excl + s2;
        float c3 = excl + s3;
        float c4 = excl + s4;

        // chunk partial in fp32 (bounded ~1e8, safe), then one double add
        float part = fabsf(c1) * w0
                   + fabsf(c2) * (w0 - 1.0f)
                   + fabsf(c3) * (w0 - 2.0f)
                   + fabsf(c4) * (w0 - 3.0f);
        acc += (double)part;

        carry += total;
        // no second barrier: parity buffer + next chunk's barrier give WAR safety
    }

    // block reduction of double acc: wave shuffle-reduce, then LDS across 4 waves
    #pragma unroll
    for (int off = 32; off > 0; off >>= 1)
        acc += __shfl_down(acc, off, 64);

    __shared__ double dtot[4];
    if (lane == 0) dtot[wave] = acc;
    __syncthreads();

    if (tid == 0) {
        double s = dtot[0] + dtot[1] + dtot[2] + dtot[3];
        atomicAdd(ws_accum, s);   // device-scope f64 atomic, 1 per block
    }
}

__global__ void wloss_finalize_kernel(const double* __restrict__ ws_accum,
                                      float* __restrict__ out)
{
    const double tc      = (double)T_LEN * (double)C_CH;      // 524288
    const double scaling = 2.0 / (tc * (tc + 1.0));
    out[0] = (float)(ws_accum[0] * scaling / (double)B_BATCH);
}

extern "C" void kernel_launch(void* const* d_in, const int* in_sizes, int n_in,
                              void* d_out, int out_size, void* d_ws, size_t ws_size,
                              hipStream_t stream)
{
    const float* pred = (const float*)d_in[0];
    const float* tru  = (const float*)d_in[1];
    double*      ws   = (double*)d_ws;
    float*       out  = (float*)d_out;

    // d_ws is re-poisoned to 0xAA before every launch -> zero the accumulator
    hipMemsetAsync(ws, 0, sizeof(double), stream);

    wloss_scan_kernel<<<NROWS, THREADS, 0, stream>>>(pred, tru, ws);
    wloss_finalize_kernel<<<1, 1, 0, stream>>>(ws, out);
}